// Round 2
// baseline (118.546 us; speedup 1.0000x reference)
//
#include <hip/hip_runtime.h>
#include <cstdint>

#define EPS 1e-5f

// LDS layout (floats). tl (conv tile) is overlaid with phase-1/2 scratch.
#define LDS_TL    0        /* 8*34*132 = 35904 : conv tile (phase 4)        */
                           /* overlay: rs[8][128] @0, cs[8][128] @1024,     */
                           /*          red[4][256] float4 @2048 (phase 1)   */
#define LDS_SH    35904    /* 8*128 */
#define LDS_SW    36928    /* 8*128 */
#define LDS_S     37952    /* 8   */
#define LDS_TM    37960    /* 72  */
#define LDS_CORN  38032    /* 32  */
#define LDS_M2    38064    /* 8   */
#define LDS_X11   38072    /* 8   */
#define LDS_X21   38080    /* 8   */
#define LDS_W1L   38088    /* 64  */
#define LDS_B1L   38152    /* 8   */
#define LDS_WTL   38160    /* 73  */
#define LDS_PS    38240    /* 64  */
#define LDS_QS    38304    /* 64  */
#define LDS_AL    38368    /* 8   */
#define LDS_BS    38376    /* 8   */
#define LDS_BETA  38384    /* 1   */
#define LDS_TOTAL 38400    /* floats -> 153600 bytes */

__global__ __launch_bounds__(1024) void fused_adaptatt(
    const float* __restrict__ x,
    const float* __restrict__ w1, const float* __restrict__ b1,
    const float* __restrict__ w3, const float* __restrict__ b3,
    const float* __restrict__ gn_w, const float* __restrict__ gn_b,
    float* __restrict__ out)
{
    extern __shared__ float lds[];
    const int bg = blockIdx.x;
    const int t  = threadIdx.x;
    const int sg = t >> 8;        // 0..3 subgroup (256 threads each)
    const int ts = t & 255;
    float* rs = lds;              // [8][128]
    float* cs = lds + 1024;       // [8][128]
    float4* red = (float4*)(lds + 2048);  // [4][256]
    const size_t pbase = (size_t)(bg * 8) * 16384;

    // ================= Phase 1: per-plane row sums & col sums =================
    for (int half = 0; half < 2; ++half) {
        int pi = half * 4 + sg;
        const float4* xp = (const float4*)(x + pbase + (size_t)pi * 16384);
        float4 csum = {0.f, 0.f, 0.f, 0.f};
        for (int i = 0; i < 16; ++i) {
            float4 v = xp[i * 256 + ts];
            csum.x += v.x; csum.y += v.y; csum.z += v.z; csum.w += v.w;
            float rsv = v.x + v.y + v.z + v.w;
            for (int m = 16; m; m >>= 1) rsv += __shfl_xor(rsv, m);
            if ((ts & 31) == 0) rs[pi * 128 + i * 8 + (ts >> 5)] = rsv;
        }
        red[sg * 256 + ts] = csum;
        __syncthreads();
        if (ts < 32) {
            float4 s = red[sg * 256 + ts];
            for (int j = 1; j < 8; ++j) {
                float4 v = red[sg * 256 + j * 32 + ts];
                s.x += v.x; s.y += v.y; s.z += v.z; s.w += v.w;
            }
            ((float4*)(cs + pi * 128))[ts] = s;
        }
        __syncthreads();
    }

    // ---- stage small weights / corners / x11 ----
    if (t < 64) lds[LDS_W1L + t] = w1[t];
    if (t >= 64 && t < 72) lds[LDS_B1L + (t - 64)] = b1[t - 64];
    if (t >= 128 && t < 136) {
        int i = t - 128;
        const float* xpp = x + pbase + (size_t)i * 16384;
        lds[LDS_CORN + i * 4 + 0] = xpp[0];
        lds[LDS_CORN + i * 4 + 1] = xpp[127];
        lds[LDS_CORN + i * 4 + 2] = xpp[127 * 128];
        lds[LDS_CORN + i * 4 + 3] = xpp[127 * 128 + 127];
    }
    if (t == 200) {   // x11 = softmax(gn_b)
        float mx = gn_b[0];
        for (int i = 1; i < 8; ++i) mx = fmaxf(mx, gn_b[i]);
        float e[8], s = 0.f;
        for (int i = 0; i < 8; ++i) { e[i] = __expf(gn_b[i] - mx); s += e[i]; }
        for (int i = 0; i < 8; ++i) lds[LDS_X11 + i] = e[i] / s;
    }
    __syncthreads();

    // ================= Phase 2: gates sh/sw (all 1024 threads) =================
    {
        int o = t >> 7, y = t & 127;
        const float inv128 = 1.f / 128.f;
        float ar = lds[LDS_B1L + o], ac = ar;
        for (int i = 0; i < 8; ++i) {
            float w = lds[LDS_W1L + o * 8 + i];
            ar += w * rs[i * 128 + y] * inv128;
            ac += w * cs[i * 128 + y] * inv128;
        }
        lds[LDS_SH + o * 128 + y] = 1.f / (1.f + __expf(-ar));
        lds[LDS_SW + o * 128 + y] = 1.f / (1.f + __expf(-ac));
    }
    if (t < 8) {
        float s = 0.f;
        for (int y = 0; y < 128; ++y) s += rs[t * 128 + y];
        lds[LDS_S + t] = s;
    }
    __syncthreads();

    if (t < 72) {   // shifted-window sums for SAME zero padding
        int i = t / 9, ky = (t % 9) / 3, kx = t % 3;
        float v = lds[LDS_S + i];
        if (ky == 0) v -= rs[i * 128 + 127]; else if (ky == 2) v -= rs[i * 128 + 0];
        if (kx == 0) v -= cs[i * 128 + 127]; else if (kx == 2) v -= cs[i * 128 + 0];
        if (ky == 0 && kx == 0) v += lds[LDS_CORN + i * 4 + 3];
        if (ky == 0 && kx == 2) v += lds[LDS_CORN + i * 4 + 2];
        if (ky == 2 && kx == 0) v += lds[LDS_CORN + i * 4 + 1];
        if (ky == 2 && kx == 2) v += lds[LDS_CORN + i * 4 + 0];
        lds[LDS_TM + t] = v;
    }
    __syncthreads();

    if (t < 8) {    // per-output-channel mean of x2
        float acc = 0.f;
        for (int j = 0; j < 72; ++j) acc += w3[t * 72 + j] * lds[LDS_TM + j];
        lds[LDS_M2 + t] = b3[t] + acc * (1.f / 16384.f);
    }
    if (t >= 128 && t < 201) {   // collapsed conv weights wt[0..71], btilde wt[72]
        int j = t - 128;
        float a = 0.f;
        if (j < 72) { for (int o = 0; o < 8; ++o) a += lds[LDS_X11 + o] * w3[o * 72 + j]; }
        else        { for (int o = 0; o < 8; ++o) a += lds[LDS_X11 + o] * b3[o]; }
        lds[LDS_WTL + j] = a;
    }
    __syncthreads();

    if (t == 0) {   // x21 = softmax(m2)
        float mx = lds[LDS_M2];
        for (int i = 1; i < 8; ++i) mx = fmaxf(mx, lds[LDS_M2 + i]);
        float e[8], s = 0.f;
        for (int i = 0; i < 8; ++i) { e[i] = __expf(lds[LDS_M2 + i] - mx); s += e[i]; }
        for (int i = 0; i < 8; ++i) lds[LDS_X21 + i] = e[i] / s;
    }
    __syncthreads();

    // ================= Phase 3: gated sum & sumsq per plane =================
    float* shl = lds + LDS_SH;
    float* swl = lds + LDS_SW;
    for (int half = 0; half < 2; ++half) {
        int pi = half * 4 + sg;
        const float4* xp = (const float4*)(x + pbase + (size_t)pi * 16384);
        float4 sw4 = ((const float4*)(swl + pi * 128))[ts & 31];
        float s = 0.f, q = 0.f;
        for (int i = 0; i < 16; ++i) {
            float4 v = xp[i * 256 + ts];
            float shv = shl[pi * 128 + i * 8 + (ts >> 5)];
            float g0 = v.x * shv * sw4.x;
            float g1 = v.y * shv * sw4.y;
            float g2 = v.z * shv * sw4.z;
            float g3 = v.w * shv * sw4.w;
            s += g0 + g1 + g2 + g3;
            q += g0 * g0 + g1 * g1 + g2 * g2 + g3 * g3;
        }
        for (int m = 16; m; m >>= 1) { s += __shfl_xor(s, m); q += __shfl_xor(q, m); }
        if ((ts & 31) == 0) {
            lds[LDS_PS + pi * 8 + (ts >> 5)] = s;
            lds[LDS_QS + pi * 8 + (ts >> 5)] = q;
        }
    }
    __syncthreads();
    if (t < 8) {
        float s = 0.f, q = 0.f;
        for (int j = 0; j < 8; ++j) { s += lds[LDS_PS + t * 8 + j]; q += lds[LDS_QS + t * 8 + j]; }
        float mu  = s * (1.f / 16384.f);
        float ex2 = q * (1.f / 16384.f);
        float var = ex2 - mu * mu;
        float inv = rsqrtf(var + EPS);
        float x21v = lds[LDS_X21 + t];
        lds[LDS_AL + t] = x21v * inv * gn_w[t];
        lds[LDS_BS + t] = x21v * (gn_b[t] - mu * inv * gn_w[t]);
    }
    __syncthreads();
    if (t == 0) {
        float s = lds[LDS_WTL + 72];
        for (int i = 0; i < 8; ++i) s += lds[LDS_BS + i];
        lds[LDS_BETA] = s;
    }
    __syncthreads();

    // ================= Phase 4: collapsed conv + gating + sigmoid + out =================
    const float beta_v = lds[LDS_BETA];
    for (int ch = 0; ch < 4; ++ch) {
        int r0 = ch * 32;
        __syncthreads();   // tile reuse guard
        // stage 8ch x 34 rows (r0-1 .. r0+32) x 132 cols (halo'd, +1 col shift)
        {
            int rr = t >> 5, c4 = t & 31;
            int g = r0 - 1 + rr;
#pragma unroll
            for (int i = 0; i < 8; ++i) {
                float4 v = {0.f, 0.f, 0.f, 0.f};
                if (g >= 0 && g < 128)
                    v = *(const float4*)(x + pbase + (size_t)i * 16384 + g * 128 + c4 * 4);
                float* d = &lds[(i * 34 + rr) * 132 + 1 + c4 * 4];
                d[0] = v.x; d[1] = v.y; d[2] = v.z; d[3] = v.w;
                if (c4 == 0)  d[-1] = 0.f;
                if (c4 == 31) d[4]  = 0.f;
                if (t < 64) {   // rows 32,33 of the tile
                    int rr2 = 32 + rr;           // rr in {0,1} here
                    int g2 = r0 - 1 + rr2;
                    float4 v2 = {0.f, 0.f, 0.f, 0.f};
                    if (g2 < 128)
                        v2 = *(const float4*)(x + pbase + (size_t)i * 16384 + g2 * 128 + c4 * 4);
                    float* d2 = &lds[(i * 34 + rr2) * 132 + 1 + c4 * 4];
                    d2[0] = v2.x; d2[1] = v2.y; d2[2] = v2.z; d2[3] = v2.w;
                    if (c4 == 0)  d2[-1] = 0.f;
                    if (c4 == 31) d2[4]  = 0.f;
                }
            }
        }
        __syncthreads();
        // compute 32 rows x 128 cols, float4 per thread
        int y = t >> 5;
        int x0 = (t & 31) * 4;
        float acc0, acc1, acc2, acc3;
        acc0 = acc1 = acc2 = acc3 = beta_v;
        float gv[8][4];
#pragma unroll
        for (int i = 0; i < 8; ++i) {
            const float* base = &lds[(i * 34 + y) * 132 + x0];
#pragma unroll
            for (int ky = 0; ky < 3; ++ky) {
                float4 va = *(const float4*)(base + ky * 132);
                float4 vb = *(const float4*)(base + ky * 132 + 4);
                float w0 = lds[LDS_WTL + i * 9 + ky * 3 + 0];
                float w1v = lds[LDS_WTL + i * 9 + ky * 3 + 1];
                float w2 = lds[LDS_WTL + i * 9 + ky * 3 + 2];
                acc0 += w0 * va.x + w1v * va.y + w2 * va.z;
                acc1 += w0 * va.y + w1v * va.z + w2 * va.w;
                acc2 += w0 * va.z + w1v * va.w + w2 * vb.x;
                acc3 += w0 * va.w + w1v * vb.x + w2 * vb.y;
                if (ky == 1) { gv[i][0] = va.y; gv[i][1] = va.z; gv[i][2] = va.w; gv[i][3] = vb.x; }
            }
            float as = lds[LDS_AL + i] * shl[i * 128 + r0 + y];
            float4 s4 = *(const float4*)(swl + i * 128 + x0);
            acc0 += as * s4.x * gv[i][0];
            acc1 += as * s4.y * gv[i][1];
            acc2 += as * s4.z * gv[i][2];
            acc3 += as * s4.w * gv[i][3];
        }
        float sg0 = 1.f / (1.f + __expf(-acc0));
        float sg1 = 1.f / (1.f + __expf(-acc1));
        float sg2 = 1.f / (1.f + __expf(-acc2));
        float sg3 = 1.f / (1.f + __expf(-acc3));
        size_t ob = pbase + (size_t)(r0 + y) * 128 + x0;
#pragma unroll
        for (int c = 0; c < 8; ++c) {
            float4 o4 = { gv[c][0] * sg0, gv[c][1] * sg1, gv[c][2] * sg2, gv[c][3] * sg3 };
            *(float4*)(out + ob + (size_t)c * 16384) = o4;
        }
    }
}

extern "C" void kernel_launch(void* const* d_in, const int* in_sizes, int n_in,
                              void* d_out, int out_size, void* d_ws, size_t ws_size,
                              hipStream_t stream) {
    (void)in_sizes; (void)n_in; (void)out_size; (void)d_ws; (void)ws_size;
    const float* x    = (const float*)d_in[0];
    const float* w1   = (const float*)d_in[1];
    const float* b1   = (const float*)d_in[2];
    const float* w3   = (const float*)d_in[3];
    const float* b3   = (const float*)d_in[4];
    const float* gn_w = (const float*)d_in[5];
    const float* gn_b = (const float*)d_in[6];
    float* out = (float*)d_out;

    hipLaunchKernelGGL(fused_adaptatt, dim3(256), dim3(1024), LDS_TOTAL * 4, stream,
                       x, w1, b1, w3, b3, gn_w, gn_b, out);
}

// Round 3
// 107.551 us; speedup vs baseline: 1.1022x; 1.1022x over previous
//
#include <hip/hip_runtime.h>
#include <cstdint>

#define EPS 1e-5f
#define TS 136   // E tile row stride in floats (128 data + 4 left pad + 4 right pad)

// ============ K1: rowsum/colsum (LDS-local) + gates sh/sw + x21 + wt ============
__global__ __launch_bounds__(1024) void k1_gates(
    const float* __restrict__ x,
    const float* __restrict__ w1, const float* __restrict__ b1,
    const float* __restrict__ w3, const float* __restrict__ b3,
    const float* __restrict__ gn_b,
    float* __restrict__ sh, float* __restrict__ sw,
    float* __restrict__ x21, float* __restrict__ wt)
{
    __shared__ float rs[1024], cs[1024];
    __shared__ float4 red[1024];
    __shared__ float w1l[64], b1l[8], corn[32], S[8], Tm[72], m2[8], x11[8];
    const int bg = blockIdx.x;
    const int t  = threadIdx.x;
    const int sg = t >> 8, ts = t & 255;
    const size_t pbase = (size_t)(bg * 8) * 16384;

    for (int half = 0; half < 2; ++half) {
        int pi = half * 4 + sg;
        const float4* xp = (const float4*)(x + pbase + (size_t)pi * 16384);
        float4 csum = {0.f, 0.f, 0.f, 0.f};
        for (int i = 0; i < 16; ++i) {
            float4 v = xp[i * 256 + ts];
            csum.x += v.x; csum.y += v.y; csum.z += v.z; csum.w += v.w;
            float rsv = v.x + v.y + v.z + v.w;
            for (int m = 16; m; m >>= 1) rsv += __shfl_xor(rsv, m);
            if ((ts & 31) == 0) rs[pi * 128 + i * 8 + (ts >> 5)] = rsv;
        }
        red[sg * 256 + ts] = csum;
        __syncthreads();
        if (ts < 32) {
            float4 s = red[sg * 256 + ts];
            for (int j = 1; j < 8; ++j) {
                float4 v = red[sg * 256 + j * 32 + ts];
                s.x += v.x; s.y += v.y; s.z += v.z; s.w += v.w;
            }
            ((float4*)(cs + pi * 128))[ts] = s;
        }
        __syncthreads();
    }

    if (t < 64) w1l[t] = w1[t];
    if (t >= 64 && t < 72) b1l[t - 64] = b1[t - 64];
    if (t >= 128 && t < 136) {
        int i = t - 128;
        const float* xpp = x + pbase + (size_t)i * 16384;
        corn[i * 4 + 0] = xpp[0];
        corn[i * 4 + 1] = xpp[127];
        corn[i * 4 + 2] = xpp[127 * 128];
        corn[i * 4 + 3] = xpp[127 * 128 + 127];
    }
    if (t == 200) {   // x11 = softmax(gn_b)
        float mx = gn_b[0];
        for (int i = 1; i < 8; ++i) mx = fmaxf(mx, gn_b[i]);
        float e[8], s = 0.f;
        for (int i = 0; i < 8; ++i) { e[i] = __expf(gn_b[i] - mx); s += e[i]; }
        for (int i = 0; i < 8; ++i) x11[i] = e[i] / s;
    }
    __syncthreads();

    {   // sh/sw: 8 o-channels x 128 positions = 1024 threads
        int o = t >> 7, y = t & 127;
        const float inv128 = 1.f / 128.f;
        float ar = b1l[o], ac = ar;
        for (int i = 0; i < 8; ++i) {
            float w = w1l[o * 8 + i];
            ar += w * rs[i * 128 + y] * inv128;
            ac += w * cs[i * 128 + y] * inv128;
        }
        sh[(bg * 8 + o) * 128 + y] = 1.f / (1.f + __expf(-ar));
        sw[(bg * 8 + o) * 128 + y] = 1.f / (1.f + __expf(-ac));
    }
    if (t < 8) {
        float s = 0.f;
        for (int y = 0; y < 128; ++y) s += rs[t * 128 + y];
        S[t] = s;
    }
    __syncthreads();

    if (t < 72) {   // shifted-window sums for SAME zero padding
        int i = t / 9, ky = (t % 9) / 3, kx = t % 3;
        float v = S[i];
        if (ky == 0) v -= rs[i * 128 + 127]; else if (ky == 2) v -= rs[i * 128 + 0];
        if (kx == 0) v -= cs[i * 128 + 127]; else if (kx == 2) v -= cs[i * 128 + 0];
        if (ky == 0 && kx == 0) v += corn[i * 4 + 3];
        if (ky == 0 && kx == 2) v += corn[i * 4 + 2];
        if (ky == 2 && kx == 0) v += corn[i * 4 + 1];
        if (ky == 2 && kx == 2) v += corn[i * 4 + 0];
        Tm[t] = v;
    }
    __syncthreads();

    if (t < 8) {    // per-output-channel mean of x2
        float acc = 0.f;
        for (int j = 0; j < 72; ++j) acc += w3[t * 72 + j] * Tm[j];
        m2[t] = b3[t] + acc * (1.f / 16384.f);
    }
    if (bg == 0 && t >= 128 && t < 201) {   // collapsed conv weights + btilde
        int j = t - 128;
        float a = 0.f;
        if (j < 72) { for (int o = 0; o < 8; ++o) a += x11[o] * w3[o * 72 + j]; }
        else        { for (int o = 0; o < 8; ++o) a += x11[o] * b3[o]; }
        wt[j] = a;
    }
    __syncthreads();

    if (t == 0) {   // x21 = softmax(m2)
        float mx = m2[0];
        for (int i = 1; i < 8; ++i) mx = fmaxf(mx, m2[i]);
        float e[8], s = 0.f;
        for (int i = 0; i < 8; ++i) { e[i] = __expf(m2[i] - mx); s += e[i]; }
        for (int i = 0; i < 8; ++i) x21[bg * 8 + i] = e[i] / s;
    }
}

// ============ K2: gated sum/sumsq per plane + alpha/beta ============
__global__ __launch_bounds__(1024) void k2_stats(
    const float* __restrict__ x, const float* __restrict__ sh,
    const float* __restrict__ sw, const float* __restrict__ x21,
    const float* __restrict__ gn_w, const float* __restrict__ gn_b,
    const float* __restrict__ wt,
    float* __restrict__ alpha, float* __restrict__ beta)
{
    __shared__ float shl[1024], swl[1024], ps[64], qs[64], bs[8];
    const int bg = blockIdx.x;
    const int t  = threadIdx.x;
    const int sg = t >> 8, ts = t & 255;
    const size_t pbase = (size_t)(bg * 8) * 16384;
    shl[t] = sh[bg * 1024 + t];
    swl[t] = sw[bg * 1024 + t];
    __syncthreads();

    for (int half = 0; half < 2; ++half) {
        int pi = half * 4 + sg;
        const float4* xp = (const float4*)(x + pbase + (size_t)pi * 16384);
        float4 sw4 = ((const float4*)(swl + pi * 128))[ts & 31];
        float s = 0.f, q = 0.f;
        for (int i = 0; i < 16; ++i) {
            float4 v = xp[i * 256 + ts];
            float shv = shl[pi * 128 + i * 8 + (ts >> 5)];
            float g0 = v.x * shv * sw4.x;
            float g1 = v.y * shv * sw4.y;
            float g2 = v.z * shv * sw4.z;
            float g3 = v.w * shv * sw4.w;
            s += g0 + g1 + g2 + g3;
            q += g0 * g0 + g1 * g1 + g2 * g2 + g3 * g3;
        }
        for (int m = 16; m; m >>= 1) { s += __shfl_xor(s, m); q += __shfl_xor(q, m); }
        if ((ts & 31) == 0) {
            ps[pi * 8 + (ts >> 5)] = s;
            qs[pi * 8 + (ts >> 5)] = q;
        }
    }
    __syncthreads();
    if (t < 8) {
        float s = 0.f, q = 0.f;
        for (int j = 0; j < 8; ++j) { s += ps[t * 8 + j]; q += qs[t * 8 + j]; }
        float mu  = s * (1.f / 16384.f);
        float ex2 = q * (1.f / 16384.f);
        float var = ex2 - mu * mu;
        float inv = rsqrtf(var + EPS);
        float x21v = x21[bg * 8 + t];
        alpha[bg * 8 + t] = x21v * inv * gn_w[t];
        bs[t] = x21v * (gn_b[t] - mu * inv * gn_w[t]);
    }
    __syncthreads();
    if (t == 0) {
        float s = wt[72];
        for (int i = 0; i < 8; ++i) s += bs[i];
        beta[bg] = s;
    }
}

// ============ K3: collapsed 8->1 conv + gating + sigmoid + output ============
// 2048 blocks (8 per bg, 16 output rows each), 256 threads, 2 rows/thread.
__global__ __launch_bounds__(256, 2) void k3_out(
    const float* __restrict__ x, const float* __restrict__ sh,
    const float* __restrict__ sw, const float* __restrict__ alpha,
    const float* __restrict__ beta, const float* __restrict__ wt,
    float* __restrict__ out)
{
    __shared__ float tl[8 * 18 * TS];   // 78336 B
    __shared__ float wtl[73], al[8];
    __shared__ float betal;
    const int blk = blockIdx.x;
    const int bg  = blk >> 3;
    const int r0  = (blk & 7) * 16;
    const int t    = threadIdx.x;
    const int lane = t & 31;
    const int cidx = t >> 5;            // staging: channel; compute: y-group
    const size_t pbase = (size_t)(bg * 8) * 16384;

    // ---- stage: ch=cidx, 18 rows (r0-1 .. r0+16), aligned b128 writes ----
    {
        const float* xc = x + pbase + (size_t)cidx * 16384 + 4 * lane;
        float* dst = tl + (cidx * 18) * TS + 4 + 4 * lane;
#pragma unroll
        for (int row = 0; row < 18; ++row) {
            int g = r0 - 1 + row;
            float4 v = {0.f, 0.f, 0.f, 0.f};
            if ((unsigned)g < 128u) v = *(const float4*)(xc + (size_t)g * 128);
            *(float4*)(dst + row * TS) = v;
        }
        if (lane == 0 || lane == 31) {   // zero pads (cols -4..-1 and 128..131)
            float* pz = tl + (cidx * 18) * TS + (lane == 0 ? 0 : 132);
            float4 z = {0.f, 0.f, 0.f, 0.f};
#pragma unroll
            for (int row = 0; row < 18; ++row) *(float4*)(pz + row * TS) = z;
        }
    }
    if (t < 73) wtl[t] = wt[t];
    else if (t < 81) al[t - 73] = alpha[bg * 8 + (t - 73)];
    else if (t == 81) betal = beta[bg];
    __syncthreads();

    const int yg = cidx;
    const int y0 = r0 + 2 * yg;
    const int x0 = 4 * lane;
    float4 accA = {betal, betal, betal, betal};
    float4 accB = accA;
    float4 gvA[8], gvB[8];

#pragma unroll
    for (int i = 0; i < 8; ++i) {
        const float* B = tl + (i * 18 + 2 * yg) * TS + 4 + x0;
        float asA = al[i] * sh[(size_t)(bg * 8 + i) * 128 + y0];
        float asB = al[i] * sh[(size_t)(bg * 8 + i) * 128 + y0 + 1];
        float4 s4 = *(const float4*)(sw + (size_t)(bg * 8 + i) * 128 + x0);
#pragma unroll
        for (int r = 0; r < 4; ++r) {
            float4 v = *(const float4*)(B + r * TS);
            float xm1 = __shfl_up(v.w, 1, 32);
            if (lane == 0)  xm1 = 0.f;          // col -1 pad
            float xp4 = __shfl_down(v.x, 1, 32);
            if (lane == 31) xp4 = 0.f;          // col 128 pad
            if (r < 3) {      // contributes to row A with ky=r
                float w0 = wtl[i * 9 + r * 3 + 0];
                float w1v = wtl[i * 9 + r * 3 + 1];
                float w2 = wtl[i * 9 + r * 3 + 2];
                accA.x += w0 * xm1  + w1v * v.x + w2 * v.y;
                accA.y += w0 * v.x  + w1v * v.y + w2 * v.z;
                accA.z += w0 * v.y  + w1v * v.z + w2 * v.w;
                accA.w += w0 * v.z  + w1v * v.w + w2 * xp4;
            }
            if (r > 0) {      // contributes to row B with ky=r-1
                int ky = r - 1;
                float w0 = wtl[i * 9 + ky * 3 + 0];
                float w1v = wtl[i * 9 + ky * 3 + 1];
                float w2 = wtl[i * 9 + ky * 3 + 2];
                accB.x += w0 * xm1  + w1v * v.x + w2 * v.y;
                accB.y += w0 * v.x  + w1v * v.y + w2 * v.z;
                accB.z += w0 * v.y  + w1v * v.z + w2 * v.w;
                accB.w += w0 * v.z  + w1v * v.w + w2 * xp4;
            }
            if (r == 1) gvA[i] = v;   // center row for output A
            if (r == 2) gvB[i] = v;   // center row for output B
        }
        accA.x += asA * s4.x * gvA[i].x;
        accA.y += asA * s4.y * gvA[i].y;
        accA.z += asA * s4.z * gvA[i].z;
        accA.w += asA * s4.w * gvA[i].w;
        accB.x += asB * s4.x * gvB[i].x;
        accB.y += asB * s4.y * gvB[i].y;
        accB.z += asB * s4.z * gvB[i].z;
        accB.w += asB * s4.w * gvB[i].w;
    }

    float4 sgA, sgB;
    sgA.x = 1.f / (1.f + __expf(-accA.x));
    sgA.y = 1.f / (1.f + __expf(-accA.y));
    sgA.z = 1.f / (1.f + __expf(-accA.z));
    sgA.w = 1.f / (1.f + __expf(-accA.w));
    sgB.x = 1.f / (1.f + __expf(-accB.x));
    sgB.y = 1.f / (1.f + __expf(-accB.y));
    sgB.z = 1.f / (1.f + __expf(-accB.z));
    sgB.w = 1.f / (1.f + __expf(-accB.w));

    size_t ob = pbase + (size_t)y0 * 128 + x0;
#pragma unroll
    for (int c = 0; c < 8; ++c) {
        float4 oA = { gvA[c].x * sgA.x, gvA[c].y * sgA.y, gvA[c].z * sgA.z, gvA[c].w * sgA.w };
        float4 oB = { gvB[c].x * sgB.x, gvB[c].y * sgB.y, gvB[c].z * sgB.z, gvB[c].w * sgB.w };
        *(float4*)(out + ob + (size_t)c * 16384)       = oA;
        *(float4*)(out + ob + (size_t)c * 16384 + 128) = oB;
    }
}

extern "C" void kernel_launch(void* const* d_in, const int* in_sizes, int n_in,
                              void* d_out, int out_size, void* d_ws, size_t ws_size,
                              hipStream_t stream) {
    (void)in_sizes; (void)n_in; (void)out_size; (void)ws_size;
    const float* x    = (const float*)d_in[0];
    const float* w1   = (const float*)d_in[1];
    const float* b1   = (const float*)d_in[2];
    const float* w3   = (const float*)d_in[3];
    const float* b3   = (const float*)d_in[4];
    const float* gn_w = (const float*)d_in[5];
    const float* gn_b = (const float*)d_in[6];
    float* out = (float*)d_out;
    float* ws  = (float*)d_ws;

    float* sh    = ws;              // 2048*128
    float* sw    = ws + 262144;     // 2048*128
    float* x21   = ws + 524288;     // 2048
    float* alpha = ws + 526336;     // 2048
    float* beta  = ws + 528384;     // 256
    float* wt    = ws + 528640;     // 73

    hipLaunchKernelGGL(k1_gates, dim3(256),  dim3(1024), 0, stream,
                       x, w1, b1, w3, b3, gn_b, sh, sw, x21, wt);
    hipLaunchKernelGGL(k2_stats, dim3(256),  dim3(1024), 0, stream,
                       x, sh, sw, x21, gn_w, gn_b, wt, alpha, beta);
    hipLaunchKernelGGL(k3_out,   dim3(2048), dim3(256),  0, stream,
                       x, sh, sw, alpha, beta, wt, out);
}